// Round 12
// baseline (141.762 us; speedup 1.0000x reference)
//
#include <hip/hip_runtime.h>
#include <hip/hip_bf16.h>

// CausalSelfAttention: B=8 T=2048 C=126 H=6 D=21
// Round 12: non-attn overhaul (attn = R11 verbatim, 47.6us).
//  prep_w: LDS 64x65 tile transpose -> coalesced read+write, 16 blocks.
//  qkv: 32 rows/block (512 blocks), waves paired on two 16-row m-tiles.
//  proj: 64 rows/block (256 blocks), wave-per-m-tile, LDS-staged stores.

#define B_ 8
#define T_ 2048
#define C_ 126
#define H_ 6
#define D_ 21
#define TC_ 378    // 3*C
#define KP_ 128    // padded GEMM inner dim
#define DP_ 32     // padded head dim
#define M_ 16384   // B*T
#define QSCALE 0.31481923469333463f   // (1/sqrt(21)) * log2(e)

typedef __hip_bfloat16 bf16;
typedef __bf16 bf16_t;
typedef __bf16 bf16x8 __attribute__((ext_vector_type(8)));
typedef float f32x4 __attribute__((ext_vector_type(4)));

__device__ __forceinline__ float ldf(const bf16* p, long i) { return __bfloat162float(p[i]); }
__device__ __forceinline__ float ldf(const float* p, long i) { return p[i]; }
__device__ __forceinline__ void stf(bf16* p, long i, float v) { p[i] = __float2bfloat16(v); }
__device__ __forceinline__ void stf(float* p, long i, float v) { p[i] = v; }

__device__ __forceinline__ unsigned int ld2(const bf16* x, long i) {
  return *(const unsigned int*)((const unsigned short*)x + i);
}
__device__ __forceinline__ unsigned int ld2(const float* x, long i) {
  const float2 f = *(const float2*)(x + i);
  union { bf16_t b[2]; unsigned int u; } cv;
  cv.b[0] = (bf16_t)f.x; cv.b[1] = (bf16_t)f.y;
  return cv.u;
}

// ------------- inline dtype probe: wave 0 -> sflag (1 = bf16) -------------
__device__ __forceinline__ void probe_dtype(const void* x, int tid, int* sflag) {
  if (tid < 64) {
    const unsigned int w = ((const unsigned int*)x)[tid * 97 + 13];
    const unsigned int e = (w >> 7) & 0xFF;
    const bool bflike = (e >= 115 && e <= 131) || ((w & 0x7FFFu) == 0);
    const unsigned long long mask = __ballot(bflike);
    if (tid == 0) *sflag = (__popcll(mask) >= 40) ? 1 : 0;
  }
  __syncthreads();
}

// ------------- prep_w: coalesced LDS tile transpose -----------------------
// 16 blocks: 0..11 -> WTa (6 n-tiles x 2 k-tiles), 12..15 -> WTp (2x2).
template <typename T>
__device__ __forceinline__ void prep_w_body(const T* __restrict__ wa,
                                            const T* __restrict__ wp,
                                            bf16_t* __restrict__ WTa,
                                            bf16_t* __restrict__ WTp,
                                            float (*tile)[65]) {
  const int id = blockIdx.x;
  const bool isA = id < 12;
  const int nt = isA ? (id % 6) : ((id - 12) & 1);
  const int kt = isA ? (id / 6) : ((id - 12) >> 1);
  const T* src = isA ? wa : wp;
  bf16_t* dst = isA ? WTa : WTp;
  const int NN = isA ? TC_ : C_;       // valid src cols (n)
  const int NR = isA ? 384 : KP_;      // dst rows (n, padded)
  const int tid = threadIdx.x;
  const int wv = tid >> 6, lane = tid & 63;

  // read: 64 k-rows x 64 n-cols, lane = n (coalesced)
#pragma unroll
  for (int rr = 0; rr < 16; ++rr) {
    const int kl = wv * 16 + rr;
    const int k = kt * 64 + kl, n = nt * 64 + lane;
    tile[kl][lane] = (k < C_ && n < NN) ? ldf(src, (long)k * NN + n) : 0.f;
  }
  __syncthreads();
  // write: 64 n-rows x 64 k-cols, lane = k (coalesced); LDS col read stride 65
#pragma unroll
  for (int rr = 0; rr < 16; ++rr) {
    const int nl = wv * 16 + rr;
    const int n = nt * 64 + nl;
    if (n < NR) dst[(long)n * KP_ + kt * 64 + lane] = (bf16_t)tile[lane][nl];
  }
}

__global__ __launch_bounds__(256) void prep_w_kernel(
    const void* __restrict__ x, const void* __restrict__ wa,
    const void* __restrict__ wp, bf16_t* __restrict__ WTa,
    bf16_t* __restrict__ WTp) {
  __shared__ float tile[64][65];
  __shared__ int sflag;
  probe_dtype(x, threadIdx.x, &sflag);
  if (sflag) prep_w_body<bf16>((const bf16*)wa, (const bf16*)wp, WTa, WTp, tile);
  else       prep_w_body<float>((const float*)wa, (const float*)wp, WTa, WTp, tile);
}

// ------------- qkv = x @ w_attn via MFMA, 32 rows/block -------------------
// Waves 0,1 -> m-tile 0 (rows m0..m0+15), waves 2,3 -> m-tile 1; within a
// pair, waves interleave the 24 n-tiles (12 each). LDS transpose stores.
#define QS_ 40   // qbuf/kbuf d-stride

template <typename T>
__device__ __forceinline__ void qkv_body(
    const T* __restrict__ x, const bf16_t* __restrict__ WT,
    bf16_t* __restrict__ Qb, bf16_t* __restrict__ Kb, bf16_t* __restrict__ VT,
    bf16_t* __restrict__ xs, bf16_t* __restrict__ qbuf,
    bf16_t* __restrict__ kbuf, bf16_t* __restrict__ vbuf) {
  const int m0 = blockIdx.x * 32;
  const int tid = threadIdx.x;
  // packed x staging: 32 rows x 64 uint slots
  for (int i = tid; i < 32 * 64; i += 256) {
    const int row = i >> 6, cp = i & 63;
    unsigned int v = 0;
    if (cp < 63) v = ld2(x, (long)(m0 + row) * C_ + 2 * cp);
    ((unsigned int*)xs)[i] = v;
  }
  // pad init: qbuf/kbuf d=21..31 zero; vbuf d=21 ones, d=22..31 zero
  for (int i = tid; i < 6 * 32 * 11; i += 256) {
    const int h = i / 352, rem = i - h * 352, t = rem / 11, d = 21 + rem % 11;
    qbuf[(h * 32 + t) * QS_ + d] = (bf16_t)0.f;
    kbuf[(h * 32 + t) * QS_ + d] = (bf16_t)0.f;
  }
  for (int i = tid; i < 6 * 11 * 32; i += 256) {
    const int h = i / 352, rem = i - h * 352, d = 21 + rem / 32, t = rem & 31;
    vbuf[(h * 32 + d) * 32 + t] = (d == 21) ? (bf16_t)1.f : (bf16_t)0.f;
  }
  __syncthreads();

  const int wv = tid >> 6, lane = tid & 63;
  const int lr = lane & 15, quad = lane >> 4;
  const int mt = wv >> 1;                      // which 16-row m-tile
  const bf16_t* ar = xs + (mt * 16 + lr) * KP_ + quad * 8;
  const bf16x8 a0 = *(const bf16x8*)(ar);
  const bf16x8 a1 = *(const bf16x8*)(ar + 32);
  const bf16x8 a2 = *(const bf16x8*)(ar + 64);
  const bf16x8 a3 = *(const bf16x8*)(ar + 96);

  for (int nt = (wv & 1); nt < 24; nt += 2) {
    const int n0 = nt * 16;
    const bf16x8* bp = (const bf16x8*)(WT + (long)(n0 + lr) * KP_ + quad * 8);
    f32x4 acc = {0.f, 0.f, 0.f, 0.f};
    acc = __builtin_amdgcn_mfma_f32_16x16x32_bf16(a0, bp[0],  acc, 0, 0, 0);
    acc = __builtin_amdgcn_mfma_f32_16x16x32_bf16(a1, bp[4],  acc, 0, 0, 0);
    acc = __builtin_amdgcn_mfma_f32_16x16x32_bf16(a2, bp[8],  acc, 0, 0, 0);
    acc = __builtin_amdgcn_mfma_f32_16x16x32_bf16(a3, bp[12], acc, 0, 0, 0);

    const int c = n0 + lr;                 // 0..383
    if (c < TC_) {
      const int which = c / C_;
      const int cc = c - which * C_;
      const int h = cc / D_, d = cc - h * D_;
#pragma unroll
      for (int r = 0; r < 4; ++r) {
        const int t = mt * 16 + quad * 4 + r;    // 0..31
        if (which == 0)
          qbuf[(h * 32 + t) * QS_ + d] = (bf16_t)(acc[r] * QSCALE);
        else if (which == 1)
          kbuf[(h * 32 + t) * QS_ + d] = (bf16_t)acc[r];
        else
          vbuf[(h * 32 + d) * 32 + t] = (bf16_t)acc[r];
      }
    }
  }
  __syncthreads();

  // ---- coalesced store phase (all rows 64 B) ----
  const int b = m0 >> 11, t0 = m0 & 2047;
  for (int i = tid; i < 384; i += 256) {   // Q,K: 192 rows each
    const int j = (i < 192) ? i : i - 192;
    const int h = j >> 5, t = j & 31;
    const int4* src = (const int4*)(((i < 192) ? qbuf : kbuf) + (h * 32 + t) * QS_);
    int4* dst = (int4*)((((i < 192) ? Qb : Kb)) + ((long)(b * H_ + h) * T_ + (t0 + t)) * DP_);
    dst[0] = src[0]; dst[1] = src[1]; dst[2] = src[2]; dst[3] = src[3];
  }
  for (int i = tid; i < 192; i += 256) {   // VT: 192 rows x 64 B
    const int h = i >> 5, d = i & 31;
    const int4* src = (const int4*)(vbuf + (h * 32 + d) * 32);
    int4* dst = (int4*)(VT + ((long)(b * H_ + h) * DP_ + d) * T_ + t0);
    dst[0] = src[0]; dst[1] = src[1]; dst[2] = src[2]; dst[3] = src[3];
  }
}

__global__ __launch_bounds__(256) void qkv_mfma(
    const void* __restrict__ x, const bf16_t* __restrict__ WT,
    bf16_t* __restrict__ Qb, bf16_t* __restrict__ Kb, bf16_t* __restrict__ VT) {
  __shared__ __align__(16) bf16_t xs[32 * KP_];
  __shared__ __align__(16) bf16_t qbuf[6 * 32 * QS_];
  __shared__ __align__(16) bf16_t kbuf[6 * 32 * QS_];
  __shared__ __align__(16) bf16_t vbuf[6 * 32 * 32];
  __shared__ int sflag;
  probe_dtype(x, threadIdx.x, &sflag);
  if (sflag) qkv_body<bf16>((const bf16*)x, WT, Qb, Kb, VT, xs, qbuf, kbuf, vbuf);
  else       qkv_body<float>((const float*)x, WT, Qb, Kb, VT, xs, qbuf, kbuf, vbuf);
}

// ------------- MFMA causal flash attention (R11 verbatim) -----------------
__global__ __launch_bounds__(256, 4) void attn_mfma(
    const bf16_t* __restrict__ Qb, const bf16_t* __restrict__ Kb,
    const bf16_t* __restrict__ VT, bf16_t* __restrict__ ATTp) {
  __shared__ __align__(16) float smem[4352];
  const int bh = blockIdx.x;
  const int pr = 63 - blockIdx.y;
  const int tid = threadIdx.x;
  const int wv = tid >> 6, lane = tid & 63;
  const int lr = lane & 15, quad = lane >> 4;
  const int q0 = pr * 32;
  const int mq = quad * 4;

  const bf16_t* Qbh = Qb + (long)bh * T_ * DP_;
  const bf16_t* Kbh = Kb + (long)bh * T_ * DP_;
  const bf16_t* VTbh = VT + (long)bh * DP_ * T_;

  const bf16x8 qf0 = *(const bf16x8*)(Qbh + (long)(q0 + lr) * DP_ + quad * 8);
  const bf16x8 qf1 = *(const bf16x8*)(Qbh + (long)(q0 + 16 + lr) * DP_ + quad * 8);

  f32x4 o00 = {0.f,0.f,0.f,0.f}, o01 = {0.f,0.f,0.f,0.f};
  f32x4 o10 = {0.f,0.f,0.f,0.f}, o11 = {0.f,0.f,0.f,0.f};
  bf16_t* plA0 = (bf16_t*)smem + wv * 2048;
  bf16_t* plA1 = plA0 + 512;
  bf16_t* plB0 = plA0 + 1024;
  bf16_t* plB1 = plA0 + 1536;
  const int rsw = ((lane ^ (lane >> 2)) << 3);
  const int wb0 = ((lr >> 3) << 4) + mq;

  int t = wv;
  for (; t + 4 <= pr; t += 8) {
    const int kbA = t * 32, kbB = (t + 4) * 32;
    const bf16x8 kA0 = *(const bf16x8*)(Kbh + (long)(kbA + lr) * DP_ + quad * 8);
    const bf16x8 kA1 = *(const bf16x8*)(Kbh + (long)(kbA + 16 + lr) * DP_ + quad * 8);
    const bf16x8 kB0 = *(const bf16x8*)(Kbh + (long)(kbB + lr) * DP_ + quad * 8);
    const bf16x8 kB1 = *(const bf16x8*)(Kbh + (long)(kbB + 16 + lr) * DP_ + quad * 8);
    const bf16x8 vA0 = *(const bf16x8*)(VTbh + (long)lr * T_ + kbA + quad * 8);
    const bf16x8 vA1 = *(const bf16x8*)(VTbh + (long)(16 + lr) * T_ + kbA + quad * 8);
    const bf16x8 vB0 = *(const bf16x8*)(VTbh + (long)lr * T_ + kbB + quad * 8);
    const bf16x8 vB1 = *(const bf16x8*)(VTbh + (long)(16 + lr) * T_ + kbB + quad * 8);

    f32x4 sA00 = {0.f,0.f,0.f,0.f}, sA01 = {0.f,0.f,0.f,0.f};
    f32x4 sA10 = {0.f,0.f,0.f,0.f}, sA11 = {0.f,0.f,0.f,0.f};
    f32x4 sB00 = {0.f,0.f,0.f,0.f}, sB01 = {0.f,0.f,0.f,0.f};
    f32x4 sB10 = {0.f,0.f,0.f,0.f}, sB11 = {0.f,0.f,0.f,0.f};
    sA00 = __builtin_amdgcn_mfma_f32_16x16x32_bf16(qf0, kA0, sA00, 0, 0, 0);
    sA01 = __builtin_amdgcn_mfma_f32_16x16x32_bf16(qf0, kA1, sA01, 0, 0, 0);
    sA10 = __builtin_amdgcn_mfma_f32_16x16x32_bf16(qf1, kA0, sA10, 0, 0, 0);
    sA11 = __builtin_amdgcn_mfma_f32_16x16x32_bf16(qf1, kA1, sA11, 0, 0, 0);
    sB00 = __builtin_amdgcn_mfma_f32_16x16x32_bf16(qf0, kB0, sB00, 0, 0, 0);
    sB01 = __builtin_amdgcn_mfma_f32_16x16x32_bf16(qf0, kB1, sB01, 0, 0, 0);
    sB10 = __builtin_amdgcn_mfma_f32_16x16x32_bf16(qf1, kB0, sB10, 0, 0, 0);
    sB11 = __builtin_amdgcn_mfma_f32_16x16x32_bf16(qf1, kB1, sB11, 0, 0, 0);

    if (t + 4 == pr) {
#pragma unroll
      for (int r = 0; r < 4; ++r) {
        if (lr > mq + r) { sB00[r] = -1e30f; sB11[r] = -1e30f; }
        sB01[r] = -1e30f;
      }
    }
#pragma unroll
    for (int r = 0; r < 4; ++r) {
      const int b0 = wb0 + r, b1 = b0 + 32;
      const int i0 = ((b0 ^ (b0 >> 2)) << 3) + (lr & 7);
      const int i1 = ((b1 ^ (b1 >> 2)) << 3) + (lr & 7);
      plA0[i0] = (bf16_t)exp2f(sA00[r]);
      plA0[i1] = (bf16_t)exp2f(sA01[r]);
      plA1[i0] = (bf16_t)exp2f(sA10[r]);
      plA1[i1] = (bf16_t)exp2f(sA11[r]);
      plB0[i0] = (bf16_t)exp2f(sB00[r]);
      plB0[i1] = (bf16_t)exp2f(sB01[r]);
      plB1[i0] = (bf16_t)exp2f(sB10[r]);
      plB1[i1] = (bf16_t)exp2f(sB11[r]);
    }
    __builtin_amdgcn_wave_barrier();
    const bf16x8 pfA0 = *(const bf16x8*)(plA0 + rsw);
    const bf16x8 pfA1 = *(const bf16x8*)(plA1 + rsw);
    const bf16x8 pfB0 = *(const bf16x8*)(plB0 + rsw);
    const bf16x8 pfB1 = *(const bf16x8*)(plB1 + rsw);
    __builtin_amdgcn_wave_barrier();

    o00 = __builtin_amdgcn_mfma_f32_16x16x32_bf16(pfA0, vA0, o00, 0, 0, 0);
    o01 = __builtin_amdgcn_mfma_f32_16x16x32_bf16(pfA0, vA1, o01, 0, 0, 0);
    o10 = __builtin_amdgcn_mfma_f32_16x16x32_bf16(pfA1, vA0, o10, 0, 0, 0);
    o11 = __builtin_amdgcn_mfma_f32_16x16x32_bf16(pfA1, vA1, o11, 0, 0, 0);
    o00 = __builtin_amdgcn_mfma_f32_16x16x32_bf16(pfB0, vB0, o00, 0, 0, 0);
    o01 = __builtin_amdgcn_mfma_f32_16x16x32_bf16(pfB0, vB1, o01, 0, 0, 0);
    o10 = __builtin_amdgcn_mfma_f32_16x16x32_bf16(pfB1, vB0, o10, 0, 0, 0);
    o11 = __builtin_amdgcn_mfma_f32_16x16x32_bf16(pfB1, vB1, o11, 0, 0, 0);
  }

  if (t <= pr) {
    const int kb = t * 32;
    const bf16x8 k0 = *(const bf16x8*)(Kbh + (long)(kb + lr) * DP_ + quad * 8);
    const bf16x8 k1 = *(const bf16x8*)(Kbh + (long)(kb + 16 + lr) * DP_ + quad * 8);
    const bf16x8 v0 = *(const bf16x8*)(VTbh + (long)lr * T_ + kb + quad * 8);
    const bf16x8 v1 = *(const bf16x8*)(VTbh + (long)(16 + lr) * T_ + kb + quad * 8);
    f32x4 s00 = {0.f,0.f,0.f,0.f}, s01 = {0.f,0.f,0.f,0.f};
    f32x4 s10 = {0.f,0.f,0.f,0.f}, s11 = {0.f,0.f,0.f,0.f};
    s00 = __builtin_amdgcn_mfma_f32_16x16x32_bf16(qf0, k0, s00, 0, 0, 0);
    s01 = __builtin_amdgcn_mfma_f32_16x16x32_bf16(qf0, k1, s01, 0, 0, 0);
    s10 = __builtin_amdgcn_mfma_f32_16x16x32_bf16(qf1, k0, s10, 0, 0, 0);
    s11 = __builtin_amdgcn_mfma_f32_16x16x32_bf16(qf1, k1, s11, 0, 0, 0);
    if (t == pr) {
#pragma unroll
      for (int r = 0; r < 4; ++r) {
        if (lr > mq + r) { s00[r] = -1e30f; s11[r] = -1e30f; }
        s01[r] = -1e30f;
      }
    }
#pragma unroll
    for (int r = 0; r < 4; ++r) {
      const int b0 = wb0 + r, b1 = b0 + 32;
      const int i0 = ((b0 ^ (b0 >> 2)) << 3) + (lr & 7);
      const int i1 = ((b1 ^ (b1 >> 2)) << 3) + (lr & 7);
      plA0[i0] = (bf16_t)exp2f(s00[r]);
      plA0[i1] = (bf16_t)exp2f(s01[r]);
      plA1[i0] = (bf16_t)exp2f(s10[r]);
      plA1[i1] = (bf16_t)exp2f(s11[r]);
    }
    __builtin_amdgcn_wave_barrier();
    const bf16x8 pf0 = *(const bf16x8*)(plA0 + rsw);
    const bf16x8 pf1 = *(const bf16x8*)(plA1 + rsw);
    __builtin_amdgcn_wave_barrier();
    o00 = __builtin_amdgcn_mfma_f32_16x16x32_bf16(pf0, v0, o00, 0, 0, 0);
    o01 = __builtin_amdgcn_mfma_f32_16x16x32_bf16(pf0, v1, o01, 0, 0, 0);
    o10 = __builtin_amdgcn_mfma_f32_16x16x32_bf16(pf1, v0, o10, 0, 0, 0);
    o11 = __builtin_amdgcn_mfma_f32_16x16x32_bf16(pf1, v1, o11, 0, 0, 0);
  }

  __syncthreads();
  {
    float* my = smem + (wv * 64 + lane) * 17;
#pragma unroll
    for (int j = 0; j < 4; ++j) {
      my[j]      = o00[j];
      my[4 + j]  = o01[j];
      my[8 + j]  = o10[j];
      my[12 + j] = o11[j];
    }
  }
  __syncthreads();

  if (wv == 0) {
    float tot[16];
#pragma unroll
    for (int j = 0; j < 16; ++j)
      tot[j] = smem[lane * 17 + j] + smem[(64 + lane) * 17 + j] +
               smem[(128 + lane) * 17 + j] + smem[(192 + lane) * 17 + j];
    const int b = bh / H_, h = bh - b * H_;
#pragma unroll
    for (int r = 0; r < 4; ++r) {
      const float rl0 = 1.f / __shfl(tot[4 + r],  (lane & 48) + 5, 64);
      const float rl1 = 1.f / __shfl(tot[12 + r], (lane & 48) + 5, 64);
      const int qA = q0 + mq + r, qB = qA + 16;
      bf16_t* opA = ATTp + (long)(b * T_ + qA) * KP_ + h * D_;
      bf16_t* opB = ATTp + (long)(b * T_ + qB) * KP_ + h * D_;
      opA[lr] = (bf16_t)(tot[r] * rl0);
      opB[lr] = (bf16_t)(tot[8 + r] * rl1);
      if (lr < 5) {
        opA[16 + lr] = (bf16_t)(tot[4 + r] * rl0);
        opB[16 + lr] = (bf16_t)(tot[12 + r] * rl1);
      }
    }
  }
}

// ------------- out = ATT @ w_proj via MFMA, 64 rows/block -----------------
#define OS_ 136   // obuf col stride (bf16)
__global__ __launch_bounds__(256) void proj_mfma(
    const void* __restrict__ x, const bf16_t* __restrict__ ATTp,
    const bf16_t* __restrict__ WT, void* __restrict__ out) {
  __shared__ __align__(16) bf16_t obuf[64 * OS_];
  __shared__ int sflag;
  probe_dtype(x, threadIdx.x, &sflag);
  const int isbf = sflag;

  const int m0 = blockIdx.x * 64;
  const int tid = threadIdx.x;
  const int wv = tid >> 6, lane = tid & 63;
  const int lr = lane & 15, quad = lane >> 4;

  const bf16x8* ap = (const bf16x8*)(ATTp + (long)(m0 + wv * 16 + lr) * KP_ + quad * 8);
  const bf16x8 a0 = ap[0], a1 = ap[4], a2 = ap[8], a3 = ap[12];

#pragma unroll
  for (int nt = 0; nt < 8; ++nt) {
    const int n0 = nt * 16;
    const bf16x8* bp = (const bf16x8*)(WT + (long)(n0 + lr) * KP_ + quad * 8);
    f32x4 acc = {0.f, 0.f, 0.f, 0.f};
    acc = __builtin_amdgcn_mfma_f32_16x16x32_bf16(a0, bp[0],  acc, 0, 0, 0);
    acc = __builtin_amdgcn_mfma_f32_16x16x32_bf16(a1, bp[4],  acc, 0, 0, 0);
    acc = __builtin_amdgcn_mfma_f32_16x16x32_bf16(a2, bp[8],  acc, 0, 0, 0);
    acc = __builtin_amdgcn_mfma_f32_16x16x32_bf16(a3, bp[12], acc, 0, 0, 0);
#pragma unroll
    for (int r = 0; r < 4; ++r)
      obuf[(wv * 16 + quad * 4 + r) * OS_ + n0 + lr] = (bf16_t)acc[r];
  }
  __syncthreads();

  // coalesced store: 64 rows x 63 dword-pairs
  for (int i = tid; i < 64 * 63; i += 256) {
    const int row = i / 63, c2 = i - row * 63;
    const bf16_t* s = obuf + row * OS_ + 2 * c2;
    if (isbf) {
      union { bf16_t b[2]; unsigned int u; } cv;
      cv.b[0] = s[0]; cv.b[1] = s[1];
      ((unsigned int*)out)[(long)(m0 + row) * 63 + c2] = cv.u;
    } else {
      float2 f;
      f.x = (float)s[0]; f.y = (float)s[1];
      ((float2*)out)[(long)(m0 + row) * 63 + c2] = f;
    }
  }
}

extern "C" void kernel_launch(void* const* d_in, const int* in_sizes, int n_in,
                              void* d_out, int out_size, void* d_ws, size_t ws_size,
                              hipStream_t stream) {
  const void* x      = d_in[0];
  const void* w_attn = d_in[1];
  const void* w_proj = d_in[2];

  char* base = (char*)d_ws;
  const long QKV = (long)48 * T_ * DP_;                    // 3,145,728 bf16 each
  bf16_t* Qb = (bf16_t*)(base + 256);
  bf16_t* Kb = Qb + QKV;
  bf16_t* VT = Kb + QKV;                                   // [bh][32][T]
  bf16_t* WTa  = VT + QKV;                                 // 384*128
  bf16_t* WTp  = WTa + 384 * KP_;                          // 128*128
  bf16_t* ATTp = WTp + KP_ * KP_;                          // 16384*128

  prep_w_kernel<<<16, 256, 0, stream>>>(x, w_attn, w_proj, WTa, WTp);
  qkv_mfma<<<M_ / 32, 256, 0, stream>>>(x, WTa, Qb, Kb, VT);
  attn_mfma<<<dim3(48, 64), 256, 0, stream>>>(Qb, Kb, VT, ATTp);
  proj_mfma<<<M_ / 64, 256, 0, stream>>>(x, ATTp, WTp, d_out);
}

// Round 14
// 140.285 us; speedup vs baseline: 1.0105x; 1.0105x over previous
//
#include <hip/hip_runtime.h>
#include <hip/hip_bf16.h>

// CausalSelfAttention: B=8 T=2048 C=126 H=6 D=21
// Round 14: revert to R11 4-kernel pipeline (coop launch fails in this
// harness). attn changes only:
//  (1) grid (48,32): block c owns superblocks {63-c, c} = 65 tile-units
//      exactly per block -> no block imbalance, no occupancy tail.
//  (2) f32->bf16 for P via manual (u+0x8000)>>16 (suspect: compiler's
//      (bf16_t) cast lowers to a multi-instr RNE sequence; VALUBusy says
//      ~1100 VALU-cyc/iter vs ~130 static).
// prep_w / qkv / proj verbatim from R11 (135.4us best).

#define B_ 8
#define T_ 2048
#define C_ 126
#define H_ 6
#define D_ 21
#define TC_ 378    // 3*C
#define KP_ 128    // padded GEMM inner dim
#define DP_ 32     // padded head dim
#define M_ 16384   // B*T
#define QSCALE 0.31481923469333463f   // (1/sqrt(21)) * log2(e)
#define QS_ 40     // qkv LDS d-stride

typedef __hip_bfloat16 bf16;
typedef __bf16 bf16_t;
typedef __bf16 bf16x8 __attribute__((ext_vector_type(8)));
typedef float f32x4 __attribute__((ext_vector_type(4)));

__device__ __forceinline__ float ldf(const bf16* p, long i) { return __bfloat162float(p[i]); }
__device__ __forceinline__ float ldf(const float* p, long i) { return p[i]; }
__device__ __forceinline__ void stf(bf16* p, long i, float v) { p[i] = __float2bfloat16(v); }
__device__ __forceinline__ void stf(float* p, long i, float v) { p[i] = v; }

__device__ __forceinline__ unsigned int ld2(const bf16* x, long i) {
  return *(const unsigned int*)((const unsigned short*)x + i);
}
__device__ __forceinline__ unsigned int ld2(const float* x, long i) {
  const float2 f = *(const float2*)(x + i);
  union { bf16_t b[2]; unsigned int u; } cv;
  cv.b[0] = (bf16_t)f.x; cv.b[1] = (bf16_t)f.y;
  return cv.u;
}

// fast f32 -> bf16 bits (round-half-up; inputs finite, no NaN path)
__device__ __forceinline__ unsigned short f2b(float f) {
  union { float f; unsigned int u; } v; v.f = f;
  return (unsigned short)((v.u + 0x8000u) >> 16);
}

// ------------- inline dtype probe: wave 0 -> sflag (1 = bf16) -------------
__device__ __forceinline__ void probe_dtype(const void* x, int tid, int* sflag) {
  if (tid < 64) {
    const unsigned int w = ((const unsigned int*)x)[tid * 97 + 13];
    const unsigned int e = (w >> 7) & 0xFF;
    const bool bflike = (e >= 115 && e <= 131) || ((w & 0x7FFFu) == 0);
    const unsigned long long mask = __ballot(bflike);
    if (tid == 0) *sflag = (__popcll(mask) >= 40) ? 1 : 0;
  }
  __syncthreads();
}

// ------------- prep: WT_attn[384][128], WT_proj[128][128] -----------------
template <typename T>
__device__ __forceinline__ void prep_w_body(const T* __restrict__ wa,
                                            const T* __restrict__ wp,
                                            bf16_t* __restrict__ WTa,
                                            bf16_t* __restrict__ WTp) {
  const int stride = gridDim.x * blockDim.x;
  const int idx0 = blockIdx.x * blockDim.x + threadIdx.x;
  for (int i = idx0; i < 384 * KP_ + KP_ * KP_; i += stride) {
    if (i < 384 * KP_) {
      const int n = i >> 7, k = i & 127;
      WTa[i] = (k < C_ && n < TC_) ? (bf16_t)ldf(wa, (long)k * TC_ + n) : (bf16_t)0.f;
    } else {
      const int j = i - 384 * KP_;
      const int n = j >> 7, k = j & 127;
      WTp[j] = (k < C_ && n < C_) ? (bf16_t)ldf(wp, (long)k * C_ + n) : (bf16_t)0.f;
    }
  }
}

__global__ __launch_bounds__(256) void prep_w_kernel(
    const void* __restrict__ x, const void* __restrict__ wa,
    const void* __restrict__ wp, bf16_t* __restrict__ WTa,
    bf16_t* __restrict__ WTp) {
  __shared__ int sflag;
  probe_dtype(x, threadIdx.x, &sflag);
  if (sflag) prep_w_body<bf16>((const bf16*)wa, (const bf16*)wp, WTa, WTp);
  else       prep_w_body<float>((const float*)wa, (const float*)wp, WTa, WTp);
}

// ------------- qkv = x @ w_attn via MFMA, LDS-transposed stores (R11) -----
template <typename T>
__device__ __forceinline__ void qkv_body(
    const T* __restrict__ x, const bf16_t* __restrict__ WT,
    bf16_t* __restrict__ Qb, bf16_t* __restrict__ Kb, bf16_t* __restrict__ VT,
    bf16_t* __restrict__ xs, bf16_t* __restrict__ qbuf,
    bf16_t* __restrict__ kbuf, bf16_t* __restrict__ vbuf) {
  const int m0 = blockIdx.x * 16;
  const int tid = threadIdx.x;
  for (int i = tid; i < 16 * 64; i += 256) {
    const int row = i >> 6, cp = i & 63;
    unsigned int v = 0;
    if (cp < 63) v = ld2(x, (long)(m0 + row) * C_ + 2 * cp);
    ((unsigned int*)xs)[i] = v;
  }
  for (int i = tid; i < 6 * 16 * 11; i += 256) {
    const int h = i / 176, rem = i - h * 176, t = rem / 11, d = 21 + rem % 11;
    qbuf[(h * 16 + t) * QS_ + d] = (bf16_t)0.f;
    kbuf[(h * 16 + t) * QS_ + d] = (bf16_t)0.f;
  }
  for (int i = tid; i < 6 * 11 * 16; i += 256) {
    const int h = i / 176, rem = i - h * 176, d = 21 + rem / 16, t = rem % 16;
    vbuf[(h * 32 + d) * 16 + t] = (d == 21) ? (bf16_t)1.f : (bf16_t)0.f;
  }
  __syncthreads();

  const int wv = tid >> 6, lane = tid & 63;
  const int lr = lane & 15, quad = lane >> 4;
  const bf16_t* ar = xs + lr * KP_ + quad * 8;
  const bf16x8 a0 = *(const bf16x8*)(ar);
  const bf16x8 a1 = *(const bf16x8*)(ar + 32);
  const bf16x8 a2 = *(const bf16x8*)(ar + 64);
  const bf16x8 a3 = *(const bf16x8*)(ar + 96);

  for (int nt = wv; nt < 24; nt += 4) {
    const int n0 = nt * 16;
    const bf16x8* bp = (const bf16x8*)(WT + (long)(n0 + lr) * KP_ + quad * 8);
    f32x4 acc = {0.f, 0.f, 0.f, 0.f};
    acc = __builtin_amdgcn_mfma_f32_16x16x32_bf16(a0, bp[0],  acc, 0, 0, 0);
    acc = __builtin_amdgcn_mfma_f32_16x16x32_bf16(a1, bp[4],  acc, 0, 0, 0);
    acc = __builtin_amdgcn_mfma_f32_16x16x32_bf16(a2, bp[8],  acc, 0, 0, 0);
    acc = __builtin_amdgcn_mfma_f32_16x16x32_bf16(a3, bp[12], acc, 0, 0, 0);

    const int c = n0 + lr;
    if (c < TC_) {
      const int which = c / C_;
      const int cc = c - which * C_;
      const int h = cc / D_, d = cc - h * D_;
#pragma unroll
      for (int r = 0; r < 4; ++r) {
        const int t = quad * 4 + r;
        if (which == 0)
          qbuf[(h * 16 + t) * QS_ + d] = (bf16_t)(acc[r] * QSCALE);
        else if (which == 1)
          kbuf[(h * 16 + t) * QS_ + d] = (bf16_t)acc[r];
        else
          vbuf[(h * 32 + d) * 16 + t] = (bf16_t)acc[r];
      }
    }
  }
  __syncthreads();

  const int b = m0 >> 11, t0 = m0 & 2047;
  for (int i = tid; i < 192; i += 256) {
    const int j = (i < 96) ? i : i - 96;
    const int h = j >> 4, t = j & 15;
    const int4* src = (const int4*)(((i < 96) ? qbuf : kbuf) + (h * 16 + t) * QS_);
    int4* dst = (int4*)((((i < 96) ? Qb : Kb)) + ((long)(b * H_ + h) * T_ + (t0 + t)) * DP_);
    dst[0] = src[0]; dst[1] = src[1]; dst[2] = src[2]; dst[3] = src[3];
  }
  for (int i = tid; i < 192; i += 256) {
    const int h = i >> 5, d = i & 31;
    const int4* src = (const int4*)(vbuf + (h * 32 + d) * 16);
    int4* dst = (int4*)(VT + ((long)(b * H_ + h) * DP_ + d) * T_ + t0);
    dst[0] = src[0]; dst[1] = src[1];
  }
}

__global__ __launch_bounds__(256) void qkv_mfma(
    const void* __restrict__ x, const bf16_t* __restrict__ WT,
    bf16_t* __restrict__ Qb, bf16_t* __restrict__ Kb, bf16_t* __restrict__ VT) {
  __shared__ __align__(16) bf16_t xs[16 * KP_];
  __shared__ __align__(16) bf16_t qbuf[6 * 16 * QS_];
  __shared__ __align__(16) bf16_t kbuf[6 * 16 * QS_];
  __shared__ __align__(16) bf16_t vbuf[6 * 32 * 16];
  __shared__ int sflag;
  probe_dtype(x, threadIdx.x, &sflag);
  if (sflag) qkv_body<bf16>((const bf16*)x, WT, Qb, Kb, VT, xs, qbuf, kbuf, vbuf);
  else       qkv_body<float>((const float*)x, WT, Qb, Kb, VT, xs, qbuf, kbuf, vbuf);
}

// ------------- MFMA causal flash attention, balanced 2-unit blocks --------
// grid (48, 32): x = bh (XCD-local), y = c; block handles superblocks
// pr in {63-c, c} sequentially = exactly 65 tile-units per block.
// Per unit: 4 waves split key-tiles (paired tiles, straight-line loads),
// additive partial merge in LDS, wave 0 epilogue. P-staging via manual
// bf16 trunc-round (u+0x8000)>>16, XOR-swizzled addresses.
__global__ __launch_bounds__(256, 4) void attn_mfma(
    const bf16_t* __restrict__ Qb, const bf16_t* __restrict__ Kb,
    const bf16_t* __restrict__ VT, bf16_t* __restrict__ ATTp) {
  __shared__ __align__(16) float smem[4352];      // 16KB staging / 17KB merge
  const int bh = blockIdx.x;
  const int cc_ = blockIdx.y;                     // 0..31
  const int tid = threadIdx.x;
  const int wv = tid >> 6, lane = tid & 63;
  const int lr = lane & 15, quad = lane >> 4;
  const int mq = quad * 4;

  const bf16_t* Qbh = Qb + (long)bh * T_ * DP_;
  const bf16_t* Kbh = Kb + (long)bh * T_ * DP_;
  const bf16_t* VTbh = VT + (long)bh * DP_ * T_;

  unsigned short* plA0 = (unsigned short*)smem + wv * 2048;
  unsigned short* plA1 = plA0 + 512;
  unsigned short* plB0 = plA0 + 1024;
  unsigned short* plB1 = plA0 + 1536;
  const int rsw = ((lane ^ (lane >> 2)) << 3);
  const int wb0 = ((lr >> 3) << 4) + mq;

  const int prs[2] = {63 - cc_, cc_};
#pragma unroll
  for (int uj = 0; uj < 2; ++uj) {
    const int pr = prs[uj];
    const int q0 = pr * 32;

    const bf16x8 qf0 = *(const bf16x8*)(Qbh + (long)(q0 + lr) * DP_ + quad * 8);
    const bf16x8 qf1 = *(const bf16x8*)(Qbh + (long)(q0 + 16 + lr) * DP_ + quad * 8);

    f32x4 o00 = {0.f,0.f,0.f,0.f}, o01 = {0.f,0.f,0.f,0.f};
    f32x4 o10 = {0.f,0.f,0.f,0.f}, o11 = {0.f,0.f,0.f,0.f};

    int t = wv;
    for (; t + 4 <= pr; t += 8) {
      const int kbA = t * 32, kbB = (t + 4) * 32;
      const bf16x8 kA0 = *(const bf16x8*)(Kbh + (long)(kbA + lr) * DP_ + quad * 8);
      const bf16x8 kA1 = *(const bf16x8*)(Kbh + (long)(kbA + 16 + lr) * DP_ + quad * 8);
      const bf16x8 kB0 = *(const bf16x8*)(Kbh + (long)(kbB + lr) * DP_ + quad * 8);
      const bf16x8 kB1 = *(const bf16x8*)(Kbh + (long)(kbB + 16 + lr) * DP_ + quad * 8);
      const bf16x8 vA0 = *(const bf16x8*)(VTbh + (long)lr * T_ + kbA + quad * 8);
      const bf16x8 vA1 = *(const bf16x8*)(VTbh + (long)(16 + lr) * T_ + kbA + quad * 8);
      const bf16x8 vB0 = *(const bf16x8*)(VTbh + (long)lr * T_ + kbB + quad * 8);
      const bf16x8 vB1 = *(const bf16x8*)(VTbh + (long)(16 + lr) * T_ + kbB + quad * 8);

      f32x4 sA00 = {0.f,0.f,0.f,0.f}, sA01 = {0.f,0.f,0.f,0.f};
      f32x4 sA10 = {0.f,0.f,0.f,0.f}, sA11 = {0.f,0.f,0.f,0.f};
      f32x4 sB00 = {0.f,0.f,0.f,0.f}, sB01 = {0.f,0.f,0.f,0.f};
      f32x4 sB10 = {0.f,0.f,0.f,0.f}, sB11 = {0.f,0.f,0.f,0.f};
      sA00 = __builtin_amdgcn_mfma_f32_16x16x32_bf16(qf0, kA0, sA00, 0, 0, 0);
      sA01 = __builtin_amdgcn_mfma_f32_16x16x32_bf16(qf0, kA1, sA01, 0, 0, 0);
      sA10 = __builtin_amdgcn_mfma_f32_16x16x32_bf16(qf1, kA0, sA10, 0, 0, 0);
      sA11 = __builtin_amdgcn_mfma_f32_16x16x32_bf16(qf1, kA1, sA11, 0, 0, 0);
      sB00 = __builtin_amdgcn_mfma_f32_16x16x32_bf16(qf0, kB0, sB00, 0, 0, 0);
      sB01 = __builtin_amdgcn_mfma_f32_16x16x32_bf16(qf0, kB1, sB01, 0, 0, 0);
      sB10 = __builtin_amdgcn_mfma_f32_16x16x32_bf16(qf1, kB0, sB10, 0, 0, 0);
      sB11 = __builtin_amdgcn_mfma_f32_16x16x32_bf16(qf1, kB1, sB11, 0, 0, 0);

      if (t + 4 == pr) {   // tile B diagonal (tile A never is: t+4<=pr)
#pragma unroll
        for (int r = 0; r < 4; ++r) {
          if (lr > mq + r) { sB00[r] = -1e30f; sB11[r] = -1e30f; }
          sB01[r] = -1e30f;
        }
      }
#pragma unroll
      for (int r = 0; r < 4; ++r) {
        const int b0 = wb0 + r, b1 = b0 + 32;
        const int i0 = ((b0 ^ (b0 >> 2)) << 3) + (lr & 7);
        const int i1 = ((b1 ^ (b1 >> 2)) << 3) + (lr & 7);
        plA0[i0] = f2b(exp2f(sA00[r]));
        plA0[i1] = f2b(exp2f(sA01[r]));
        plA1[i0] = f2b(exp2f(sA10[r]));
        plA1[i1] = f2b(exp2f(sA11[r]));
        plB0[i0] = f2b(exp2f(sB00[r]));
        plB0[i1] = f2b(exp2f(sB01[r]));
        plB1[i0] = f2b(exp2f(sB10[r]));
        plB1[i1] = f2b(exp2f(sB11[r]));
      }
      __builtin_amdgcn_wave_barrier();
      const bf16x8 pfA0 = *(const bf16x8*)(plA0 + rsw);
      const bf16x8 pfA1 = *(const bf16x8*)(plA1 + rsw);
      const bf16x8 pfB0 = *(const bf16x8*)(plB0 + rsw);
      const bf16x8 pfB1 = *(const bf16x8*)(plB1 + rsw);
      __builtin_amdgcn_wave_barrier();

      o00 = __builtin_amdgcn_mfma_f32_16x16x32_bf16(pfA0, vA0, o00, 0, 0, 0);
      o01 = __builtin_amdgcn_mfma_f32_16x16x32_bf16(pfA0, vA1, o01, 0, 0, 0);
      o10 = __builtin_amdgcn_mfma_f32_16x16x32_bf16(pfA1, vA0, o10, 0, 0, 0);
      o11 = __builtin_amdgcn_mfma_f32_16x16x32_bf16(pfA1, vA1, o11, 0, 0, 0);
      o00 = __builtin_amdgcn_mfma_f32_16x16x32_bf16(pfB0, vB0, o00, 0, 0, 0);
      o01 = __builtin_amdgcn_mfma_f32_16x16x32_bf16(pfB0, vB1, o01, 0, 0, 0);
      o10 = __builtin_amdgcn_mfma_f32_16x16x32_bf16(pfB1, vB0, o10, 0, 0, 0);
      o11 = __builtin_amdgcn_mfma_f32_16x16x32_bf16(pfB1, vB1, o11, 0, 0, 0);
    }

    if (t <= pr) {        // single-tile tail
      const int kb = t * 32;
      const bf16x8 k0 = *(const bf16x8*)(Kbh + (long)(kb + lr) * DP_ + quad * 8);
      const bf16x8 k1 = *(const bf16x8*)(Kbh + (long)(kb + 16 + lr) * DP_ + quad * 8);
      const bf16x8 v0 = *(const bf16x8*)(VTbh + (long)lr * T_ + kb + quad * 8);
      const bf16x8 v1 = *(const bf16x8*)(VTbh + (long)(16 + lr) * T_ + kb + quad * 8);
      f32x4 s00 = {0.f,0.f,0.f,0.f}, s01 = {0.f,0.f,0.f,0.f};
      f32x4 s10 = {0.f,0.f,0.f,0.f}, s11 = {0.f,0.f,0.f,0.f};
      s00 = __builtin_amdgcn_mfma_f32_16x16x32_bf16(qf0, k0, s00, 0, 0, 0);
      s01 = __builtin_amdgcn_mfma_f32_16x16x32_bf16(qf0, k1, s01, 0, 0, 0);
      s10 = __builtin_amdgcn_mfma_f32_16x16x32_bf16(qf1, k0, s10, 0, 0, 0);
      s11 = __builtin_amdgcn_mfma_f32_16x16x32_bf16(qf1, k1, s11, 0, 0, 0);
      if (t == pr) {
#pragma unroll
        for (int r = 0; r < 4; ++r) {
          if (lr > mq + r) { s00[r] = -1e30f; s11[r] = -1e30f; }
          s01[r] = -1e30f;
        }
      }
#pragma unroll
      for (int r = 0; r < 4; ++r) {
        const int b0 = wb0 + r, b1 = b0 + 32;
        const int i0 = ((b0 ^ (b0 >> 2)) << 3) + (lr & 7);
        const int i1 = ((b1 ^ (b1 >> 2)) << 3) + (lr & 7);
        plA0[i0] = f2b(exp2f(s00[r]));
        plA0[i1] = f2b(exp2f(s01[r]));
        plA1[i0] = f2b(exp2f(s10[r]));
        plA1[i1] = f2b(exp2f(s11[r]));
      }
      __builtin_amdgcn_wave_barrier();
      const bf16x8 pf0 = *(const bf16x8*)(plA0 + rsw);
      const bf16x8 pf1 = *(const bf16x8*)(plA1 + rsw);
      __builtin_amdgcn_wave_barrier();
      o00 = __builtin_amdgcn_mfma_f32_16x16x32_bf16(pf0, v0, o00, 0, 0, 0);
      o01 = __builtin_amdgcn_mfma_f32_16x16x32_bf16(pf0, v1, o01, 0, 0, 0);
      o10 = __builtin_amdgcn_mfma_f32_16x16x32_bf16(pf1, v0, o10, 0, 0, 0);
      o11 = __builtin_amdgcn_mfma_f32_16x16x32_bf16(pf1, v1, o11, 0, 0, 0);
    }

    // ---- merge: partials additive (no-max softmax) ----
    __syncthreads();
    {
      float* my = smem + (wv * 64 + lane) * 17;
#pragma unroll
      for (int j = 0; j < 4; ++j) {
        my[j]      = o00[j];
        my[4 + j]  = o01[j];
        my[8 + j]  = o10[j];
        my[12 + j] = o11[j];
      }
    }
    __syncthreads();

    if (wv == 0) {
      float tot[16];
#pragma unroll
      for (int j = 0; j < 16; ++j)
        tot[j] = smem[lane * 17 + j] + smem[(64 + lane) * 17 + j] +
                 smem[(128 + lane) * 17 + j] + smem[(192 + lane) * 17 + j];
      const int b = bh / H_, h = bh - b * H_;
#pragma unroll
      for (int r = 0; r < 4; ++r) {
        const float rl0 = 1.f / __shfl(tot[4 + r],  (lane & 48) + 5, 64);
        const float rl1 = 1.f / __shfl(tot[12 + r], (lane & 48) + 5, 64);
        const int qA = q0 + mq + r, qB = qA + 16;
        bf16_t* opA = ATTp + (long)(b * T_ + qA) * KP_ + h * D_;
        bf16_t* opB = ATTp + (long)(b * T_ + qB) * KP_ + h * D_;
        opA[lr] = (bf16_t)(tot[r] * rl0);
        opB[lr] = (bf16_t)(tot[8 + r] * rl1);
        if (lr < 5) {
          opA[16 + lr] = (bf16_t)(tot[4 + r] * rl0);
          opB[16 + lr] = (bf16_t)(tot[12 + r] * rl1);
        }
      }
    }
    __syncthreads();   // protect merge area before next unit's staging
  }
}

// ------------- out = ATT @ w_proj via MFMA (R11) --------------------------
__global__ __launch_bounds__(256) void proj_mfma(
    const void* __restrict__ x, const bf16_t* __restrict__ ATTp,
    const bf16_t* __restrict__ WT, void* __restrict__ out) {
  __shared__ int sflag;
  probe_dtype(x, threadIdx.x, &sflag);
  const int isbf = sflag;

  const int m0 = blockIdx.x * 16;
  const int tid = threadIdx.x;
  const int wv = tid >> 6, lane = tid & 63;
  const int lr = lane & 15, quad = lane >> 4;

  const bf16x8* ap = (const bf16x8*)(ATTp + (long)(m0 + lr) * KP_ + quad * 8);
  const bf16x8 a0 = ap[0], a1 = ap[4], a2 = ap[8], a3 = ap[12];

  for (int nt = wv; nt < 8; nt += 4) {
    const int n0 = nt * 16;
    const bf16x8* bp = (const bf16x8*)(WT + (long)(n0 + lr) * KP_ + quad * 8);
    f32x4 acc = {0.f, 0.f, 0.f, 0.f};
    acc = __builtin_amdgcn_mfma_f32_16x16x32_bf16(a0, bp[0],  acc, 0, 0, 0);
    acc = __builtin_amdgcn_mfma_f32_16x16x32_bf16(a1, bp[4],  acc, 0, 0, 0);
    acc = __builtin_amdgcn_mfma_f32_16x16x32_bf16(a2, bp[8],  acc, 0, 0, 0);
    acc = __builtin_amdgcn_mfma_f32_16x16x32_bf16(a3, bp[12], acc, 0, 0, 0);

    const int c = n0 + lr;
    if (c < C_) {
#pragma unroll
      for (int r = 0; r < 4; ++r) {
        const int m = m0 + quad * 4 + r;
        if (isbf) stf((bf16*)out,  (long)m * C_ + c, acc[r]);
        else      stf((float*)out, (long)m * C_ + c, acc[r]);
      }
    }
  }
}

extern "C" void kernel_launch(void* const* d_in, const int* in_sizes, int n_in,
                              void* d_out, int out_size, void* d_ws, size_t ws_size,
                              hipStream_t stream) {
  const void* x      = d_in[0];
  const void* w_attn = d_in[1];
  const void* w_proj = d_in[2];

  char* base = (char*)d_ws;
  const long QKV = (long)48 * T_ * DP_;                    // 3,145,728 bf16 each
  bf16_t* Qb = (bf16_t*)(base + 256);
  bf16_t* Kb = Qb + QKV;
  bf16_t* VT = Kb + QKV;                                   // [bh][32][T]
  bf16_t* WTa  = VT + QKV;                                 // 384*128
  bf16_t* WTp  = WTa + 384 * KP_;                          // 128*128
  bf16_t* ATTp = WTp + KP_ * KP_;                          // 16384*128

  prep_w_kernel<<<64, 256, 0, stream>>>(x, w_attn, w_proj, WTa, WTp);
  qkv_mfma<<<M_ / 16, 256, 0, stream>>>(x, WTa, Qb, Kb, VT);
  attn_mfma<<<dim3(48, 32), 256, 0, stream>>>(Qb, Kb, VT, ATTp);
  proj_mfma<<<M_ / 16, 256, 0, stream>>>(x, ATTp, WTp, d_out);
}

// Round 16
// 137.660 us; speedup vs baseline: 1.0298x; 1.0191x over previous
//
#include <hip/hip_runtime.h>
#include <hip/hip_bf16.h>

// CausalSelfAttention: B=8 T=2048 C=126 H=6 D=21
// Round 16: R15 with the pad-init RACE fixed. R15's int4 zeroing and the
// vbuf ones-row write touched the same addresses from different threads
// with no barrier -> ones-row sometimes zeroed -> l=0 -> 1/l=inf -> NaN.
// Fix: __syncthreads() between zero phase and ones-row write.
//  prep_w: LDS 64x65 tile transpose (coalesced both sides, 16 blocks).
//  attn/proj: R11 verbatim (best attn: 47.6us).

#define B_ 8
#define T_ 2048
#define C_ 126
#define H_ 6
#define D_ 21
#define TC_ 378    // 3*C
#define KP_ 128    // padded GEMM inner dim
#define DP_ 32     // padded head dim
#define M_ 16384   // B*T
#define QSCALE 0.31481923469333463f   // (1/sqrt(21)) * log2(e)
#define QS_ 40     // qkv LDS d-stride

typedef __hip_bfloat16 bf16;
typedef __bf16 bf16_t;
typedef __bf16 bf16x8 __attribute__((ext_vector_type(8)));
typedef float f32x4 __attribute__((ext_vector_type(4)));

__device__ __forceinline__ float ldf(const bf16* p, long i) { return __bfloat162float(p[i]); }
__device__ __forceinline__ float ldf(const float* p, long i) { return p[i]; }
__device__ __forceinline__ void stf(bf16* p, long i, float v) { p[i] = __float2bfloat16(v); }
__device__ __forceinline__ void stf(float* p, long i, float v) { p[i] = v; }

__device__ __forceinline__ unsigned int ld2(const bf16* x, long i) {
  return *(const unsigned int*)((const unsigned short*)x + i);
}
__device__ __forceinline__ unsigned int ld2(const float* x, long i) {
  const float2 f = *(const float2*)(x + i);
  union { bf16_t b[2]; unsigned int u; } cv;
  cv.b[0] = (bf16_t)f.x; cv.b[1] = (bf16_t)f.y;
  return cv.u;
}

// ------------- inline dtype probe: wave 0 -> sflag (1 = bf16) -------------
__device__ __forceinline__ void probe_dtype(const void* x, int tid, int* sflag) {
  if (tid < 64) {
    const unsigned int w = ((const unsigned int*)x)[tid * 97 + 13];
    const unsigned int e = (w >> 7) & 0xFF;
    const bool bflike = (e >= 115 && e <= 131) || ((w & 0x7FFFu) == 0);
    const unsigned long long mask = __ballot(bflike);
    if (tid == 0) *sflag = (__popcll(mask) >= 40) ? 1 : 0;
  }
  __syncthreads();
}

// ------------- prep_w: coalesced LDS tile transpose -----------------------
// 16 blocks: 0..11 -> WTa (6 n-tiles x 2 k-tiles), 12..15 -> WTp (2x2).
template <typename T>
__device__ __forceinline__ void prep_w_body(const T* __restrict__ wa,
                                            const T* __restrict__ wp,
                                            bf16_t* __restrict__ WTa,
                                            bf16_t* __restrict__ WTp,
                                            float (*tile)[65]) {
  const int id = blockIdx.x;
  const bool isA = id < 12;
  const int nt = isA ? (id % 6) : ((id - 12) & 1);
  const int kt = isA ? (id / 6) : ((id - 12) >> 1);
  const T* src = isA ? wa : wp;
  bf16_t* dst = isA ? WTa : WTp;
  const int NN = isA ? TC_ : C_;       // valid src cols (n)
  const int NR = isA ? 384 : KP_;      // dst rows (n, padded)
  const int tid = threadIdx.x;
  const int wv = tid >> 6, lane = tid & 63;

  // read: 64 k-rows x 64 n-cols, lane = n (coalesced)
#pragma unroll
  for (int rr = 0; rr < 16; ++rr) {
    const int kl = wv * 16 + rr;
    const int k = kt * 64 + kl, n = nt * 64 + lane;
    tile[kl][lane] = (k < C_ && n < NN) ? ldf(src, (long)k * NN + n) : 0.f;
  }
  __syncthreads();
  // write: 64 n-rows x 64 k-cols, lane = k (coalesced); LDS col stride 65
#pragma unroll
  for (int rr = 0; rr < 16; ++rr) {
    const int nl = wv * 16 + rr;
    const int n = nt * 64 + nl;
    if (n < NR) dst[(long)n * KP_ + kt * 64 + lane] = (bf16_t)tile[lane][nl];
  }
}

__global__ __launch_bounds__(256) void prep_w_kernel(
    const void* __restrict__ x, const void* __restrict__ wa,
    const void* __restrict__ wp, bf16_t* __restrict__ WTa,
    bf16_t* __restrict__ WTp) {
  __shared__ float tile[64][65];
  __shared__ int sflag;
  probe_dtype(x, threadIdx.x, &sflag);
  if (sflag) prep_w_body<bf16>((const bf16*)wa, (const bf16*)wp, WTa, WTp, tile);
  else       prep_w_body<float>((const float*)wa, (const float*)wp, WTa, WTp, tile);
}

// ------------- qkv = x @ w_attn via MFMA, LDS-transposed stores -----------
template <typename T>
__device__ __forceinline__ void qkv_body(
    const T* __restrict__ x, const bf16_t* __restrict__ WT,
    bf16_t* __restrict__ Qb, bf16_t* __restrict__ Kb, bf16_t* __restrict__ VT,
    bf16_t* __restrict__ xs, bf16_t* __restrict__ qbuf,
    bf16_t* __restrict__ kbuf, bf16_t* __restrict__ vbuf) {
  const int m0 = blockIdx.x * 16;
  const int tid = threadIdx.x;
  for (int i = tid; i < 16 * 64; i += 256) {
    const int row = i >> 6, cp = i & 63;
    unsigned int v = 0;
    if (cp < 63) v = ld2(x, (long)(m0 + row) * C_ + 2 * cp);
    ((unsigned int*)xs)[i] = v;
  }
  // vectorized pad init: zero qbuf/kbuf/vbuf with int4 stores...
  {
    const int4 z4 = {0, 0, 0, 0};
    for (int i = tid; i < 480; i += 256) {
      ((int4*)qbuf)[i] = z4;
      ((int4*)kbuf)[i] = z4;
    }
    for (int i = tid; i < 384; i += 256) ((int4*)vbuf)[i] = z4;
  }
  __syncthreads();   // RACE FIX: zeros fully visible before ones-row write
  if (tid < 96) vbuf[(((tid >> 4) * 32) + D_) * 16 + (tid & 15)] = (bf16_t)1.f;
  __syncthreads();

  const int wv = tid >> 6, lane = tid & 63;
  const int lr = lane & 15, quad = lane >> 4;
  const bf16_t* ar = xs + lr * KP_ + quad * 8;
  const bf16x8 a0 = *(const bf16x8*)(ar);
  const bf16x8 a1 = *(const bf16x8*)(ar + 32);
  const bf16x8 a2 = *(const bf16x8*)(ar + 64);
  const bf16x8 a3 = *(const bf16x8*)(ar + 96);

  for (int nt = wv; nt < 24; nt += 4) {
    const int n0 = nt * 16;
    const bf16x8* bp = (const bf16x8*)(WT + (long)(n0 + lr) * KP_ + quad * 8);
    f32x4 acc = {0.f, 0.f, 0.f, 0.f};
    acc = __builtin_amdgcn_mfma_f32_16x16x32_bf16(a0, bp[0],  acc, 0, 0, 0);
    acc = __builtin_amdgcn_mfma_f32_16x16x32_bf16(a1, bp[4],  acc, 0, 0, 0);
    acc = __builtin_amdgcn_mfma_f32_16x16x32_bf16(a2, bp[8],  acc, 0, 0, 0);
    acc = __builtin_amdgcn_mfma_f32_16x16x32_bf16(a3, bp[12], acc, 0, 0, 0);

    const int c = n0 + lr;
    if (c < TC_) {
      const int which = c / C_;
      const int cc = c - which * C_;
      const int h = cc / D_, d = cc - h * D_;
#pragma unroll
      for (int r = 0; r < 4; ++r) {
        const int t = quad * 4 + r;
        if (which == 0)
          qbuf[(h * 16 + t) * QS_ + d] = (bf16_t)(acc[r] * QSCALE);
        else if (which == 1)
          kbuf[(h * 16 + t) * QS_ + d] = (bf16_t)acc[r];
        else
          vbuf[(h * 32 + d) * 16 + t] = (bf16_t)acc[r];
      }
    }
  }
  __syncthreads();

  const int b = m0 >> 11, t0 = m0 & 2047;
  for (int i = tid; i < 192; i += 256) {
    const int j = (i < 96) ? i : i - 96;
    const int h = j >> 4, t = j & 15;
    const int4* src = (const int4*)(((i < 96) ? qbuf : kbuf) + (h * 16 + t) * QS_);
    int4* dst = (int4*)((((i < 96) ? Qb : Kb)) + ((long)(b * H_ + h) * T_ + (t0 + t)) * DP_);
    dst[0] = src[0]; dst[1] = src[1]; dst[2] = src[2]; dst[3] = src[3];
  }
  for (int i = tid; i < 192; i += 256) {
    const int h = i >> 5, d = i & 31;
    const int4* src = (const int4*)(vbuf + (h * 32 + d) * 16);
    int4* dst = (int4*)(VT + ((long)(b * H_ + h) * DP_ + d) * T_ + t0);
    dst[0] = src[0]; dst[1] = src[1];
  }
}

__global__ __launch_bounds__(256) void qkv_mfma(
    const void* __restrict__ x, const bf16_t* __restrict__ WT,
    bf16_t* __restrict__ Qb, bf16_t* __restrict__ Kb, bf16_t* __restrict__ VT) {
  __shared__ __align__(16) bf16_t xs[16 * KP_];
  __shared__ __align__(16) bf16_t qbuf[6 * 16 * QS_];
  __shared__ __align__(16) bf16_t kbuf[6 * 16 * QS_];
  __shared__ __align__(16) bf16_t vbuf[6 * 32 * 16];
  __shared__ int sflag;
  probe_dtype(x, threadIdx.x, &sflag);
  if (sflag) qkv_body<bf16>((const bf16*)x, WT, Qb, Kb, VT, xs, qbuf, kbuf, vbuf);
  else       qkv_body<float>((const float*)x, WT, Qb, Kb, VT, xs, qbuf, kbuf, vbuf);
}

// ------------- MFMA causal flash attention (R11 verbatim, 47.6us) ---------
// grid (48, 64): x = bh (XCD-local), y -> pr = 63-y (long blocks first).
// Wave wv owns tiles {wv, wv+4, ...} <= pr, processed in PAIRS (t, t+4):
// 8 K/V loads straight-line, 8 S-MFMA, 32 exp2, one LDS round, 8 PV-MFMA.
__global__ __launch_bounds__(256, 4) void attn_mfma(
    const bf16_t* __restrict__ Qb, const bf16_t* __restrict__ Kb,
    const bf16_t* __restrict__ VT, bf16_t* __restrict__ ATTp) {
  __shared__ __align__(16) float smem[4352];
  const int bh = blockIdx.x;
  const int pr = 63 - blockIdx.y;
  const int tid = threadIdx.x;
  const int wv = tid >> 6, lane = tid & 63;
  const int lr = lane & 15, quad = lane >> 4;
  const int q0 = pr * 32;
  const int mq = quad * 4;

  const bf16_t* Qbh = Qb + (long)bh * T_ * DP_;
  const bf16_t* Kbh = Kb + (long)bh * T_ * DP_;
  const bf16_t* VTbh = VT + (long)bh * DP_ * T_;

  const bf16x8 qf0 = *(const bf16x8*)(Qbh + (long)(q0 + lr) * DP_ + quad * 8);
  const bf16x8 qf1 = *(const bf16x8*)(Qbh + (long)(q0 + 16 + lr) * DP_ + quad * 8);

  f32x4 o00 = {0.f,0.f,0.f,0.f}, o01 = {0.f,0.f,0.f,0.f};
  f32x4 o10 = {0.f,0.f,0.f,0.f}, o11 = {0.f,0.f,0.f,0.f};
  bf16_t* plA0 = (bf16_t*)smem + wv * 2048;
  bf16_t* plA1 = plA0 + 512;
  bf16_t* plB0 = plA0 + 1024;
  bf16_t* plB1 = plA0 + 1536;
  const int rsw = ((lane ^ (lane >> 2)) << 3);
  const int wb0 = ((lr >> 3) << 4) + mq;

  int t = wv;
  for (; t + 4 <= pr; t += 8) {
    const int kbA = t * 32, kbB = (t + 4) * 32;
    const bf16x8 kA0 = *(const bf16x8*)(Kbh + (long)(kbA + lr) * DP_ + quad * 8);
    const bf16x8 kA1 = *(const bf16x8*)(Kbh + (long)(kbA + 16 + lr) * DP_ + quad * 8);
    const bf16x8 kB0 = *(const bf16x8*)(Kbh + (long)(kbB + lr) * DP_ + quad * 8);
    const bf16x8 kB1 = *(const bf16x8*)(Kbh + (long)(kbB + 16 + lr) * DP_ + quad * 8);
    const bf16x8 vA0 = *(const bf16x8*)(VTbh + (long)lr * T_ + kbA + quad * 8);
    const bf16x8 vA1 = *(const bf16x8*)(VTbh + (long)(16 + lr) * T_ + kbA + quad * 8);
    const bf16x8 vB0 = *(const bf16x8*)(VTbh + (long)lr * T_ + kbB + quad * 8);
    const bf16x8 vB1 = *(const bf16x8*)(VTbh + (long)(16 + lr) * T_ + kbB + quad * 8);

    f32x4 sA00 = {0.f,0.f,0.f,0.f}, sA01 = {0.f,0.f,0.f,0.f};
    f32x4 sA10 = {0.f,0.f,0.f,0.f}, sA11 = {0.f,0.f,0.f,0.f};
    f32x4 sB00 = {0.f,0.f,0.f,0.f}, sB01 = {0.f,0.f,0.f,0.f};
    f32x4 sB10 = {0.f,0.f,0.f,0.f}, sB11 = {0.f,0.f,0.f,0.f};
    sA00 = __builtin_amdgcn_mfma_f32_16x16x32_bf16(qf0, kA0, sA00, 0, 0, 0);
    sA01 = __builtin_amdgcn_mfma_f32_16x16x32_bf16(qf0, kA1, sA01, 0, 0, 0);
    sA10 = __builtin_amdgcn_mfma_f32_16x16x32_bf16(qf1, kA0, sA10, 0, 0, 0);
    sA11 = __builtin_amdgcn_mfma_f32_16x16x32_bf16(qf1, kA1, sA11, 0, 0, 0);
    sB00 = __builtin_amdgcn_mfma_f32_16x16x32_bf16(qf0, kB0, sB00, 0, 0, 0);
    sB01 = __builtin_amdgcn_mfma_f32_16x16x32_bf16(qf0, kB1, sB01, 0, 0, 0);
    sB10 = __builtin_amdgcn_mfma_f32_16x16x32_bf16(qf1, kB0, sB10, 0, 0, 0);
    sB11 = __builtin_amdgcn_mfma_f32_16x16x32_bf16(qf1, kB1, sB11, 0, 0, 0);

    if (t + 4 == pr) {
#pragma unroll
      for (int r = 0; r < 4; ++r) {
        if (lr > mq + r) { sB00[r] = -1e30f; sB11[r] = -1e30f; }
        sB01[r] = -1e30f;
      }
    }
#pragma unroll
    for (int r = 0; r < 4; ++r) {
      const int b0 = wb0 + r, b1 = b0 + 32;
      const int i0 = ((b0 ^ (b0 >> 2)) << 3) + (lr & 7);
      const int i1 = ((b1 ^ (b1 >> 2)) << 3) + (lr & 7);
      plA0[i0] = (bf16_t)exp2f(sA00[r]);
      plA0[i1] = (bf16_t)exp2f(sA01[r]);
      plA1[i0] = (bf16_t)exp2f(sA10[r]);
      plA1[i1] = (bf16_t)exp2f(sA11[r]);
      plB0[i0] = (bf16_t)exp2f(sB00[r]);
      plB0[i1] = (bf16_t)exp2f(sB01[r]);
      plB1[i0] = (bf16_t)exp2f(sB10[r]);
      plB1[i1] = (bf16_t)exp2f(sB11[r]);
    }
    __builtin_amdgcn_wave_barrier();
    const bf16x8 pfA0 = *(const bf16x8*)(plA0 + rsw);
    const bf16x8 pfA1 = *(const bf16x8*)(plA1 + rsw);
    const bf16x8 pfB0 = *(const bf16x8*)(plB0 + rsw);
    const bf16x8 pfB1 = *(const bf16x8*)(plB1 + rsw);
    __builtin_amdgcn_wave_barrier();

    o00 = __builtin_amdgcn_mfma_f32_16x16x32_bf16(pfA0, vA0, o00, 0, 0, 0);
    o01 = __builtin_amdgcn_mfma_f32_16x16x32_bf16(pfA0, vA1, o01, 0, 0, 0);
    o10 = __builtin_amdgcn_mfma_f32_16x16x32_bf16(pfA1, vA0, o10, 0, 0, 0);
    o11 = __builtin_amdgcn_mfma_f32_16x16x32_bf16(pfA1, vA1, o11, 0, 0, 0);
    o00 = __builtin_amdgcn_mfma_f32_16x16x32_bf16(pfB0, vB0, o00, 0, 0, 0);
    o01 = __builtin_amdgcn_mfma_f32_16x16x32_bf16(pfB0, vB1, o01, 0, 0, 0);
    o10 = __builtin_amdgcn_mfma_f32_16x16x32_bf16(pfB1, vB0, o10, 0, 0, 0);
    o11 = __builtin_amdgcn_mfma_f32_16x16x32_bf16(pfB1, vB1, o11, 0, 0, 0);
  }

  if (t <= pr) {
    const int kb = t * 32;
    const bf16x8 k0 = *(const bf16x8*)(Kbh + (long)(kb + lr) * DP_ + quad * 8);
    const bf16x8 k1 = *(const bf16x8*)(Kbh + (long)(kb + 16 + lr) * DP_ + quad * 8);
    const bf16x8 v0 = *(const bf16x8*)(VTbh + (long)lr * T_ + kb + quad * 8);
    const bf16x8 v1 = *(const bf16x8*)(VTbh + (long)(16 + lr) * T_ + kb + quad * 8);
    f32x4 s00 = {0.f,0.f,0.f,0.f}, s01 = {0.f,0.f,0.f,0.f};
    f32x4 s10 = {0.f,0.f,0.f,0.f}, s11 = {0.f,0.f,0.f,0.f};
    s00 = __builtin_amdgcn_mfma_f32_16x16x32_bf16(qf0, k0, s00, 0, 0, 0);
    s01 = __builtin_amdgcn_mfma_f32_16x16x32_bf16(qf0, k1, s01, 0, 0, 0);
    s10 = __builtin_amdgcn_mfma_f32_16x16x32_bf16(qf1, k0, s10, 0, 0, 0);
    s11 = __builtin_amdgcn_mfma_f32_16x16x32_bf16(qf1, k1, s11, 0, 0, 0);
    if (t == pr) {
#pragma unroll
      for (int r = 0; r < 4; ++r) {
        if (lr > mq + r) { s00[r] = -1e30f; s11[r] = -1e30f; }
        s01[r] = -1e30f;
      }
    }
#pragma unroll
    for (int r = 0; r < 4; ++r) {
      const int b0 = wb0 + r, b1 = b0 + 32;
      const int i0 = ((b0 ^ (b0 >> 2)) << 3) + (lr & 7);
      const int i1 = ((b1 ^ (b1 >> 2)) << 3) + (lr & 7);
      plA0[i0] = (bf16_t)exp2f(s00[r]);
      plA0[i1] = (bf16_t)exp2f(s01[r]);
      plA1[i0] = (bf16_t)exp2f(s10[r]);
      plA1[i1] = (bf16_t)exp2f(s11[r]);
    }
    __builtin_amdgcn_wave_barrier();
    const bf16x8 pf0 = *(const bf16x8*)(plA0 + rsw);
    const bf16x8 pf1 = *(const bf16x8*)(plA1 + rsw);
    __builtin_amdgcn_wave_barrier();
    o00 = __builtin_amdgcn_mfma_f32_16x16x32_bf16(pf0, v0, o00, 0, 0, 0);
    o01 = __builtin_amdgcn_mfma_f32_16x16x32_bf16(pf0, v1, o01, 0, 0, 0);
    o10 = __builtin_amdgcn_mfma_f32_16x16x32_bf16(pf1, v0, o10, 0, 0, 0);
    o11 = __builtin_amdgcn_mfma_f32_16x16x32_bf16(pf1, v1, o11, 0, 0, 0);
  }

  __syncthreads();
  {
    float* my = smem + (wv * 64 + lane) * 17;
#pragma unroll
    for (int j = 0; j < 4; ++j) {
      my[j]      = o00[j];
      my[4 + j]  = o01[j];
      my[8 + j]  = o10[j];
      my[12 + j] = o11[j];
    }
  }
  __syncthreads();

  if (wv == 0) {
    float tot[16];
#pragma unroll
    for (int j = 0; j < 16; ++j)
      tot[j] = smem[lane * 17 + j] + smem[(64 + lane) * 17 + j] +
               smem[(128 + lane) * 17 + j] + smem[(192 + lane) * 17 + j];
    const int b = bh / H_, h = bh - b * H_;
#pragma unroll
    for (int r = 0; r < 4; ++r) {
      const float rl0 = 1.f / __shfl(tot[4 + r],  (lane & 48) + 5, 64);
      const float rl1 = 1.f / __shfl(tot[12 + r], (lane & 48) + 5, 64);
      const int qA = q0 + mq + r, qB = qA + 16;
      bf16_t* opA = ATTp + (long)(b * T_ + qA) * KP_ + h * D_;
      bf16_t* opB = ATTp + (long)(b * T_ + qB) * KP_ + h * D_;
      opA[lr] = (bf16_t)(tot[r] * rl0);
      opB[lr] = (bf16_t)(tot[8 + r] * rl1);
      if (lr < 5) {
        opA[16 + lr] = (bf16_t)(tot[4 + r] * rl0);
        opB[16 + lr] = (bf16_t)(tot[12 + r] * rl1);
      }
    }
  }
}

// ------------- out = ATT @ w_proj via MFMA (R11 verbatim) -----------------
__global__ __launch_bounds__(256) void proj_mfma(
    const void* __restrict__ x, const bf16_t* __restrict__ ATTp,
    const bf16_t* __restrict__ WT, void* __restrict__ out) {
  __shared__ int sflag;
  probe_dtype(x, threadIdx.x, &sflag);
  const int isbf = sflag;

  const int m0 = blockIdx.x * 16;
  const int tid = threadIdx.x;
  const int wv = tid >> 6, lane = tid & 63;
  const int lr = lane & 15, quad = lane >> 4;

  const bf16x8* ap = (const bf16x8*)(ATTp + (long)(m0 + lr) * KP_ + quad * 8);
  const bf16x8 a0 = ap[0], a1 = ap[4], a2 = ap[8], a3 = ap[12];

  for (int nt = wv; nt < 8; nt += 4) {
    const int n0 = nt * 16;
    const bf16x8* bp = (const bf16x8*)(WT + (long)(n0 + lr) * KP_ + quad * 8);
    f32x4 acc = {0.f, 0.f, 0.f, 0.f};
    acc = __builtin_amdgcn_mfma_f32_16x16x32_bf16(a0, bp[0],  acc, 0, 0, 0);
    acc = __builtin_amdgcn_mfma_f32_16x16x32_bf16(a1, bp[4],  acc, 0, 0, 0);
    acc = __builtin_amdgcn_mfma_f32_16x16x32_bf16(a2, bp[8],  acc, 0, 0, 0);
    acc = __builtin_amdgcn_mfma_f32_16x16x32_bf16(a3, bp[12], acc, 0, 0, 0);

    const int c = n0 + lr;
    if (c < C_) {
#pragma unroll
      for (int r = 0; r < 4; ++r) {
        const int m = m0 + quad * 4 + r;
        if (isbf) stf((bf16*)out,  (long)m * C_ + c, acc[r]);
        else      stf((float*)out, (long)m * C_ + c, acc[r]);
      }
    }
  }
}

extern "C" void kernel_launch(void* const* d_in, const int* in_sizes, int n_in,
                              void* d_out, int out_size, void* d_ws, size_t ws_size,
                              hipStream_t stream) {
  const void* x      = d_in[0];
  const void* w_attn = d_in[1];
  const void* w_proj = d_in[2];

  char* base = (char*)d_ws;
  const long QKV = (long)48 * T_ * DP_;                    // 3,145,728 bf16 each
  bf16_t* Qb = (bf16_t*)(base + 256);
  bf16_t* Kb = Qb + QKV;
  bf16_t* VT = Kb + QKV;                                   // [bh][32][T]
  bf16_t* WTa  = VT + QKV;                                 // 384*128
  bf16_t* WTp  = WTa + 384 * KP_;                          // 128*128
  bf16_t* ATTp = WTp + KP_ * KP_;                          // 16384*128

  prep_w_kernel<<<16, 256, 0, stream>>>(x, w_attn, w_proj, WTa, WTp);
  qkv_mfma<<<M_ / 16, 256, 0, stream>>>(x, WTa, Qb, Kb, VT);
  attn_mfma<<<dim3(48, 64), 256, 0, stream>>>(Qb, Kb, VT, ATTp);
  proj_mfma<<<M_ / 16, 256, 0, stream>>>(x, ATTp, WTp, d_out);
}